// Round 1
// baseline (295.061 us; speedup 1.0000x reference)
//
#include <hip/hip_runtime.h>
#include <math.h>

#define B_  128
#define N_  16
#define T_  200
#define H_  64
#define J1  80
#define J2  40
#define NEGV -4294967295.0f   // -2^32 + 1

__device__ __forceinline__ float sigmoidf_(float x) {
    return 1.0f / (1.0f + __expf(-x));
}

// --- prep 0: combine W1 slices.  wac = W1a + W1c ; wbc = W1b - W1c -------
__global__ void prep_w(const float* __restrict__ W1,
                       float* __restrict__ wac, float* __restrict__ wbc) {
    int idx = blockIdx.x * 256 + threadIdx.x;          // idx = h*80 + j
    if (idx < H_ * J1) {
        wac[idx] = W1[idx]            + W1[128 * J1 + idx];
        wbc[idx] = W1[64 * J1 + idx]  - W1[128 * J1 + idx];
    }
}

// --- prep 1: QW[bn][j] = b1[j] + sum_h q[bn][h] * wac[h][j] --------------
__global__ void prep_qw(const float* __restrict__ q,
                        const float* __restrict__ wac,
                        const float* __restrict__ b1,
                        float* __restrict__ QW) {
    int idx = blockIdx.x * 256 + threadIdx.x;          // (bn, j/4)
    if (idx >= B_ * N_ * (J1 / 4)) return;
    int bn = idx / (J1 / 4);
    int j  = (idx % (J1 / 4)) * 4;
    float4 acc = *(const float4*)(b1 + j);
    const float* qp = q + bn * H_;
    for (int h = 0; h < H_; ++h) {
        float qh = qp[h];
        float4 w = *(const float4*)(wac + h * J1 + j);
        acc.x = fmaf(qh, w.x, acc.x);
        acc.y = fmaf(qh, w.y, acc.y);
        acc.z = fmaf(qh, w.z, acc.z);
        acc.w = fmaf(qh, w.w, acc.w);
    }
    *(float4*)(QW + bn * J1 + j) = acc;
}

// --- prep 2: KW[bt][j] = sum_h k[bt][h] * wbc[h][j] ----------------------
__global__ void prep_kw(const float* __restrict__ k,
                        const float* __restrict__ wbc,
                        float* __restrict__ KW) {
    int idx = blockIdx.x * 256 + threadIdx.x;          // (bt, j/4)
    if (idx >= B_ * T_ * (J1 / 4)) return;
    int bt = idx / (J1 / 4);
    int j  = (idx % (J1 / 4)) * 4;
    float4 acc = make_float4(0.f, 0.f, 0.f, 0.f);
    const float* kp = k + bt * H_;
    for (int h = 0; h < H_; ++h) {
        float kh = kp[h];
        float4 w = *(const float4*)(wbc + h * J1 + j);
        acc.x = fmaf(kh, w.x, acc.x);
        acc.y = fmaf(kh, w.y, acc.y);
        acc.z = fmaf(kh, w.z, acc.z);
        acc.w = fmaf(kh, w.w, acc.w);
    }
    *(float4*)(KW + bt * J1 + j) = acc;
}

// --- main: one block per (b,n); thread t owns key position t -------------
template <bool USE_WS>
__global__ __launch_bounds__(256) void attn_main(
        const float* __restrict__ queries, const float* __restrict__ keys,
        const int*   __restrict__ keys_length,
        const float* __restrict__ W1, const float* __restrict__ b1,
        const float* __restrict__ W2, const float* __restrict__ b2,
        const float* __restrict__ W3, const float* __restrict__ b3,
        const float* __restrict__ QW, const float* __restrict__ KW,
        float* __restrict__ out) {
    const int tid = threadIdx.x;
    const int bn  = blockIdx.x;        // 0..2047
    const int b   = bn >> 4;

    __shared__ float kT[H_][T_ + 1];   // 64 x 201, pad kills bank conflicts
    __shared__ float wsm[256];
    __shared__ float part[256];
    __shared__ float red[8];
    __shared__ float QWq[J1];

    // stage keys transposed: kT[h][t]
    for (int idx = tid; idx < T_ * H_; idx += 256) {
        int t = idx >> 6, h = idx & 63;
        kT[h][t] = keys[(b * T_ + t) * H_ + h];
    }
    if (!USE_WS) {
        if (tid < J1) {
            float acc = b1[tid];
            const float* qp = queries + bn * H_;
            for (int h = 0; h < H_; ++h)
                acc = fmaf(qp[h], W1[h * J1 + tid] + W1[(128 + h) * J1 + tid], acc);
            QWq[tid] = acc;
        }
    }
    __syncthreads();

    const int   tt = (tid < T_) ? tid : 0;   // clamp so inactive lanes read valid data
    const float* qp = queries + bn * H_;     // block-uniform -> s_load

    float z1[J1];
    if (USE_WS) {
        const float* QWp = QW + bn * J1;                 // uniform
        const float* KWp = KW + (size_t)(b * T_ + tt) * J1;
        #pragma unroll
        for (int j = 0; j < J1; j += 4) {
            float4 kw = *(const float4*)(KWp + j);
            z1[j]     = QWp[j]     + kw.x;
            z1[j + 1] = QWp[j + 1] + kw.y;
            z1[j + 2] = QWp[j + 2] + kw.z;
            z1[j + 3] = QWp[j + 3] + kw.w;
        }
    } else {
        #pragma unroll
        for (int j = 0; j < J1; ++j) z1[j] = QWq[j];
    }

    // layer 1: z1[j] += (q_h * k_h) * W1d[h][j]   (+ k_h*(W1b-W1c) if no ws)
    for (int h = 0; h < H_; ++h) {
        float kh = kT[h][tt];
        float qk = qp[h] * kh;
        const float* Wd = W1 + (192 + h) * J1;           // uniform -> s_load
        if (USE_WS) {
            #pragma unroll
            for (int j = 0; j < J1; ++j)
                z1[j] = fmaf(qk, Wd[j], z1[j]);
        } else {
            const float* Wb = W1 + (64 + h) * J1;
            const float* Wc = W1 + (128 + h) * J1;
            #pragma unroll
            for (int j = 0; j < J1; ++j)
                z1[j] = fmaf(qk, Wd[j], fmaf(kh, Wb[j] - Wc[j], z1[j]));
        }
    }

    // layer 2
    float z2[J2];
    #pragma unroll
    for (int m = 0; m < J2; ++m) z2[m] = b2[m];
    #pragma unroll
    for (int j = 0; j < J1; ++j) {
        float x = sigmoidf_(z1[j]);
        const float* w2 = W2 + j * J2;                   // uniform -> s_load
        #pragma unroll
        for (int m = 0; m < J2; ++m) z2[m] = fmaf(x, w2[m], z2[m]);
    }

    // layer 3
    float z3 = b3[0];
    #pragma unroll
    for (int m = 0; m < J2; ++m) z3 = fmaf(sigmoidf_(z2[m]), W3[m], z3);

    // mask + scale (matches reference order: mask to NEG, then /sqrt(H))
    const int L = keys_length[b];
    float s = (tid < T_) ? ((tid < L) ? z3 : NEGV) * 0.125f : -3.0e38f;

    // softmax across the block (200 valid lanes)
    float mx = s;
    #pragma unroll
    for (int off = 32; off > 0; off >>= 1) mx = fmaxf(mx, __shfl_xor(mx, off));
    if ((tid & 63) == 0) red[tid >> 6] = mx;
    __syncthreads();
    mx = fmaxf(fmaxf(red[0], red[1]), fmaxf(red[2], red[3]));

    float e = (tid < T_) ? __expf(s - mx) : 0.0f;        // masked t: exp(-5e8)=0
    float sm = e;
    #pragma unroll
    for (int off = 32; off > 0; off >>= 1) sm += __shfl_xor(sm, off);
    __syncthreads();                                     // red[0..3] fully read
    if ((tid & 63) == 0) red[4 + (tid >> 6)] = sm;
    __syncthreads();
    sm = red[4] + red[5] + red[6] + red[7];

    wsm[tid] = (tid < T_) ? (e / sm) : 0.0f;
    __syncthreads();

    // out[h] = sum_t w[t] * kT[h][t]; 4 waves each take 50 t's
    {
        int h = tid & 63, p = tid >> 6;
        float acc = 0.f;
        int t0 = p * 50;
        for (int t = t0; t < t0 + 50; ++t)
            acc = fmaf(wsm[t], kT[h][t], acc);
        part[tid] = acc;
    }
    __syncthreads();
    if (tid < 64) {
        float o = part[tid] + part[64 + tid] + part[128 + tid] + part[192 + tid];
        out[bn * H_ + tid] = o;
    }
}

extern "C" void kernel_launch(void* const* d_in, const int* in_sizes, int n_in,
                              void* d_out, int out_size, void* d_ws, size_t ws_size,
                              hipStream_t stream) {
    const float* queries = (const float*)d_in[0];
    const float* keys    = (const float*)d_in[1];
    const int*   klen    = (const int*)  d_in[2];
    const float* W1 = (const float*)d_in[3];
    const float* b1 = (const float*)d_in[4];
    const float* W2 = (const float*)d_in[5];
    const float* b2 = (const float*)d_in[6];
    const float* W3 = (const float*)d_in[7];
    const float* b3 = (const float*)d_in[8];
    float* out = (float*)d_out;

    const size_t need = (size_t)(2 * H_ * J1 + B_ * N_ * J1 + B_ * T_ * J1) * sizeof(float);

    if (ws_size >= need) {
        float* wac = (float*)d_ws;
        float* wbc = wac + H_ * J1;
        float* QW  = wbc + H_ * J1;
        float* KW  = QW + B_ * N_ * J1;
        prep_w <<<dim3((H_ * J1 + 255) / 256),           dim3(256), 0, stream>>>(W1, wac, wbc);
        prep_qw<<<dim3((B_ * N_ * (J1/4) + 255) / 256),  dim3(256), 0, stream>>>(queries, wac, b1, QW);
        prep_kw<<<dim3((B_ * T_ * (J1/4) + 255) / 256),  dim3(256), 0, stream>>>(keys, wbc, KW);
        attn_main<true><<<dim3(B_ * N_), dim3(256), 0, stream>>>(
            queries, keys, klen, W1, b1, W2, b2, W3, b3, QW, KW, out);
    } else {
        attn_main<false><<<dim3(B_ * N_), dim3(256), 0, stream>>>(
            queries, keys, klen, W1, b1, W2, b2, W3, b3,
            (const float*)nullptr, (const float*)nullptr, out);
    }
}